// Round 1
// baseline (4142.470 us; speedup 1.0000x reference)
//
#include <hip/hip_runtime.h>
#include <hip/hip_fp16.h>

#define N_IN   100000
#define N_OUT  200000
#define C_IN   128
#define C_OUT  64
#define NK     27
#define MM     100000
#define BN_EPS 1e-5f

#define TILE_M 128   // fallback path tile
#define APAD   136   // fallback LDS row stride (bf16 elems)

// ---- sorted-CSR main path geometry ----
#define TILE_R 100           // output rows per tile (2000*100 == N_OUT exactly)
#define NTILE  2000
#define NBINS  (NTILE * NK)  // 54000 bins keyed by (tile, k)
#define LROW   68            // LDS accumulator row stride in floats (pad vs 64)
#define RECCAP 3600000       // >= 2.7M + NBINS*15 worst-case padded records

typedef short bf16x8 __attribute__((ext_vector_type(8)));
typedef float f32x4  __attribute__((ext_vector_type(4)));

__device__ __forceinline__ unsigned pack2_bf16(float a, float b) {
  unsigned ua = __float_as_uint(a);
  unsigned ub = __float_as_uint(b);
  ua = (ua + 0x7FFFu + ((ua >> 16) & 1u)) >> 16;          // low half
  ub = (ub + 0x7FFFu + ((ub >> 16) & 1u)) & 0xFFFF0000u;  // high half
  return ua | ub;
}

// Combined converter:
//  blocks [0, xblocks):  x f32 [N_IN][C_IN] -> xb bf16 (packed pairs), 8 floats/thread
//  blocks [xblocks, ...): weight [k][ci][co] f32 -> wt [k][co][ci] bf16
__global__ void convert_kernel(const float* __restrict__ x, unsigned* __restrict__ xb,
                               const float* __restrict__ w, unsigned* __restrict__ wt,
                               int xblocks) {
  if ((int)blockIdx.x < xblocks) {
    int id = blockIdx.x * 256 + threadIdx.x;          // [0, 1.6M)
    const float4* xs = (const float4*)x;
    float4 v0 = xs[2 * id];
    float4 v1 = xs[2 * id + 1];
    uint4 o;
    o.x = pack2_bf16(v0.x, v0.y);
    o.y = pack2_bf16(v0.z, v0.w);
    o.z = pack2_bf16(v1.x, v1.y);
    o.w = pack2_bf16(v1.z, v1.w);
    ((uint4*)xb)[id] = o;
  } else {
    int pidx = (blockIdx.x - xblocks) * 256 + threadIdx.x;  // [0, 27*4096)
    int k   = pidx >> 12;
    int rem = pidx & 4095;
    int co  = rem >> 6;
    int ci0 = (rem & 63) * 2;
    const float* wk = w + (size_t)k * C_IN * C_OUT;
    float a = wk[ci0 * C_OUT + co];
    float b = wk[(ci0 + 1) * C_OUT + co];
    wt[pidx] = pack2_bf16(a, b);
  }
}

// ---------- phase A: counting sort of (k,m) pairs by (out_tile, k) ----------
__global__ void hist_kernel(const int* __restrict__ out_map, int* __restrict__ cnt) {
  int m = blockIdx.x * 256 + threadIdx.x;
  int k = blockIdx.y;
  if (m < MM) {
    int o = out_map[k * MM + m];
    atomicAdd(&cnt[(o / TILE_R) * NK + k], 1);
  }
}

// single-block exclusive scan over NBINS bins; each bin padded to multiple of 16
__global__ void scan_kernel(const int* __restrict__ cnt,
                            int* __restrict__ off,
                            int* __restrict__ cur) {
  __shared__ int part[256];
  const int t = threadIdx.x;
  const int PER = (NBINS + 255) / 256;  // 211
  const int s0 = t * PER;
  const int s1 = (s0 + PER < NBINS) ? (s0 + PER) : NBINS;
  int sum = 0;
  for (int i = s0; i < s1; ++i) sum += (cnt[i] + 15) & ~15;
  part[t] = sum;
  __syncthreads();
  if (t == 0) {
    int acc = 0;
    for (int i = 0; i < 256; ++i) { int v = part[i]; part[i] = acc; acc += v; }
  }
  __syncthreads();
  int run = part[t];
  for (int i = s0; i < s1; ++i) {
    off[i] = run; cur[i] = run;
    run += (cnt[i] + 15) & ~15;
  }
  if (s1 == NBINS) off[NBINS] = run;
}

// rec = (in << 7) | out_local; bit31 set == invalid (pad slots stay 0x80808080)
__global__ void scatter_rec_kernel(const int* __restrict__ in_map,
                                   const int* __restrict__ out_map,
                                   int* __restrict__ cur,
                                   unsigned* __restrict__ rec) {
  int m = blockIdx.x * 256 + threadIdx.x;
  int k = blockIdx.y;
  if (m < MM) {
    int o = out_map[k * MM + m];
    int tile = o / TILE_R;
    int ol = o - tile * TILE_R;
    int pos = atomicAdd(&cur[tile * NK + k], 1);
    rec[pos] = ((unsigned)in_map[k * MM + m] << 7) | (unsigned)ol;
  }
}

// ---------- phase B: per-tile gather-GEMM with LDS accumulation ----------
// block = 4 waves; wave w owns ci slice [w*32, w*32+32).  No barriers in k loop.
// Each 16-row chunk: 1 gathered A uint4/lane, 4 MFMAs (C=0), ds_add_f32 partials.
// Tile rows are owned exclusively by this block -> plain global store, no atomics.
__global__ __launch_bounds__(256, 4) void conv_tile_kernel(
    const uint4* __restrict__ xb,            // [N_IN][16] 16B-chunks (256 B/row)
    const unsigned short* __restrict__ wt,   // [k][co][ci] bf16
    const unsigned* __restrict__ rec,
    const int* __restrict__ off,
    float* __restrict__ out,
    float* __restrict__ ws)
{
  __shared__ float Lacc[TILE_R * LROW];      // 27.2 KB
  __shared__ float red[2][4][64];            // 2 KB, BN partial sums

  const int t    = threadIdx.x;
  const int tile = blockIdx.x;
  const int wave = t >> 6;
  const int lane = t & 63;
  const int quad = lane >> 4;
  const int l15  = lane & 15;
  const int xoff = wave * 4 + quad;          // uint4 index inside 256B x-row
  const int eoff = wave * 32 + quad * 8;     // bf16 element offset (ci)

  for (int i = t; i < TILE_R * LROW; i += 256) Lacc[i] = 0.f;
  __syncthreads();

  for (int k = 0; k < NK; ++k) {
    const int s = off[tile * NK + k];
    const int e = off[tile * NK + k + 1];
    if (s >= e) continue;

    // B fragments for this wave's ci slice, all 4 col-tiles, held in VGPRs
    const unsigned short* wkp = wt + (size_t)k * (C_OUT * C_IN) + l15 * C_IN + eoff;
    const bf16x8 bf0 = *(const bf16x8*)(wkp);
    const bf16x8 bf1 = *(const bf16x8*)(wkp + 16 * C_IN);
    const bf16x8 bf2 = *(const bf16x8*)(wkp + 32 * C_IN);
    const bf16x8 bf3 = *(const bf16x8*)(wkp + 48 * C_IN);

    // software pipeline: rec 2 chunks ahead, A-gather 1 chunk ahead
    unsigned r0 = rec[s + l15];
    unsigned r1 = (s + 16 < e) ? rec[s + 16 + l15] : 0x80808080u;
    uint4 a0 = xb[(size_t)((r0 & 0x80000000u) ? 0u : (r0 >> 7)) * 16 + xoff];

    for (int c = s; c < e; c += 16) {
      unsigned r2 = (c + 32 < e) ? rec[c + 32 + l15] : 0x80808080u;
      uint4 a1 = xb[(size_t)((r1 & 0x80000000u) ? 0u : (r1 >> 7)) * 16 + xoff];

      bf16x8 fa = *(const bf16x8*)&a0;
      const f32x4 z = (f32x4){0.f, 0.f, 0.f, 0.f};
      f32x4 acc0 = __builtin_amdgcn_mfma_f32_16x16x32_bf16(fa, bf0, z, 0, 0, 0);
      f32x4 acc1 = __builtin_amdgcn_mfma_f32_16x16x32_bf16(fa, bf1, z, 0, 0, 0);
      f32x4 acc2 = __builtin_amdgcn_mfma_f32_16x16x32_bf16(fa, bf2, z, 0, 0, 0);
      f32x4 acc3 = __builtin_amdgcn_mfma_f32_16x16x32_bf16(fa, bf3, z, 0, 0, 0);

      // D layout: col = ct*16 + l15, row(in chunk) = quad*4 + i; rec for row j
      // lives in lane j (j<16).  Invalid rows (pad) are skipped.
      #pragma unroll
      for (int i = 0; i < 4; ++i) {
        unsigned rr = __shfl(r0, quad * 4 + i);
        if (!(rr & 0x80000000u)) {
          float* dst = &Lacc[(rr & 127u) * LROW + l15];
          atomicAdd(dst +  0, acc0[i]);
          atomicAdd(dst + 16, acc1[i]);
          atomicAdd(dst + 32, acc2[i]);
          atomicAdd(dst + 48, acc3[i]);
        }
      }
      r0 = r1; r1 = r2; a0 = a1;
    }
  }
  __syncthreads();

  // fused BN statistics: column sums / sumsq over this tile's 100 rows
  {
    const int col = t & 63, g = t >> 6;
    float s = 0.f, q = 0.f;
    for (int r = g; r < TILE_R; r += 4) {
      float v = Lacc[r * LROW + col];
      s += v; q += v * v;
    }
    red[0][g][col] = s; red[1][g][col] = q;
  }
  __syncthreads();
  if (t < 64) {
    float S = red[0][0][t] + red[0][1][t] + red[0][2][t] + red[0][3][t];
    float Q = red[1][0][t] + red[1][1][t] + red[1][2][t] + red[1][3][t];
    unsafeAtomicAdd(&ws[t], S);
    unsafeAtomicAdd(&ws[64 + t], Q);
  }
  // non-atomic tile store (rows exclusively owned)
  for (int idx = t; idx < TILE_R * 16; idx += 256) {
    int r = idx >> 4, c4 = idx & 15;
    float4 v = *(const float4*)&Lacc[r * LROW + c4 * 4];
    ((float4*)out)[(size_t)(tile * TILE_R + r) * 16 + c4] = v;
  }
}

// ---------- legacy fallback (fp32 atomics into d_out) ----------
__global__ __launch_bounds__(256) void scatter_f32_kernel(
    const float* __restrict__ x,
    const unsigned short* __restrict__ wt,
    const int* __restrict__ in_map,
    const int* __restrict__ out_map,
    float* __restrict__ outf)
{
  __shared__ unsigned short Als[TILE_M * APAD];
  __shared__ unsigned short Bls[C_OUT * APAD];
  __shared__ int om[TILE_M];

  const int t = threadIdx.x;
  const int k = blockIdx.y;
  const int mbase = blockIdx.x * TILE_M;

  if (t < TILE_M) {
    int m = mbase + t;
    om[t] = (m < MM) ? out_map[k * MM + m] : 0;
  }
  {
    const uint4* src = (const uint4*)(wt + (size_t)k * C_OUT * C_IN);
    #pragma unroll
    for (int i = 0; i < 4; ++i) {
      int ch  = t + i * 256;
      int co  = ch >> 4;
      int ci0 = (ch & 15) * 8;
      *(uint4*)&Bls[co * APAD + ci0] = src[ch];
    }
  }
  {
    int r    = t >> 1;
    int half = t & 1;
    int m    = mbase + r;
    int src  = (m < MM) ? in_map[k * MM + m] : 0;
    const float4* xr = (const float4*)(x + (size_t)src * C_IN) + half * 16;
    uint2* dst = (uint2*)&Als[r * APAD + half * 64];
    #pragma unroll
    for (int j = 0; j < 16; ++j) {
      float4 v = xr[j];
      dst[j] = make_uint2(pack2_bf16(v.x, v.y), pack2_bf16(v.z, v.w));
    }
  }
  __syncthreads();

  const int wave = t >> 6;
  const int lane = t & 63;
  const int quad = lane >> 4;
  const int l15  = lane & 15;
  const int rb   = wave * 32;

  f32x4 acc[2][4];
  #pragma unroll
  for (int i = 0; i < 2; ++i)
    #pragma unroll
    for (int j = 0; j < 4; ++j)
      acc[i][j] = (f32x4){0.f, 0.f, 0.f, 0.f};

  #pragma unroll
  for (int kk = 0; kk < 4; ++kk) {
    const int koff = kk * 32 + quad * 8;
    bf16x8 a0 = *(const bf16x8*)&Als[(rb + l15) * APAD + koff];
    bf16x8 a1 = *(const bf16x8*)&Als[(rb + 16 + l15) * APAD + koff];
    bf16x8 b0 = *(const bf16x8*)&Bls[(l15) * APAD + koff];
    bf16x8 b1 = *(const bf16x8*)&Bls[(16 + l15) * APAD + koff];
    bf16x8 b2 = *(const bf16x8*)&Bls[(32 + l15) * APAD + koff];
    bf16x8 b3 = *(const bf16x8*)&Bls[(48 + l15) * APAD + koff];
    acc[0][0] = __builtin_amdgcn_mfma_f32_16x16x32_bf16(a0, b0, acc[0][0], 0, 0, 0);
    acc[0][1] = __builtin_amdgcn_mfma_f32_16x16x32_bf16(a0, b1, acc[0][1], 0, 0, 0);
    acc[0][2] = __builtin_amdgcn_mfma_f32_16x16x32_bf16(a0, b2, acc[0][2], 0, 0, 0);
    acc[0][3] = __builtin_amdgcn_mfma_f32_16x16x32_bf16(a0, b3, acc[0][3], 0, 0, 0);
    acc[1][0] = __builtin_amdgcn_mfma_f32_16x16x32_bf16(a1, b0, acc[1][0], 0, 0, 0);
    acc[1][1] = __builtin_amdgcn_mfma_f32_16x16x32_bf16(a1, b1, acc[1][1], 0, 0, 0);
    acc[1][2] = __builtin_amdgcn_mfma_f32_16x16x32_bf16(a1, b2, acc[1][2], 0, 0, 0);
    acc[1][3] = __builtin_amdgcn_mfma_f32_16x16x32_bf16(a1, b3, acc[1][3], 0, 0, 0);
  }

  #pragma unroll
  for (int rt = 0; rt < 2; ++rt) {
    int rloc = rb + rt * 16 + quad * 4;
    int4 o4 = *(const int4*)&om[rloc];
    int mrow = mbase + rloc;
    #pragma unroll
    for (int ct = 0; ct < 4; ++ct) {
      f32x4 v = acc[rt][ct];
      int col = ct * 16 + l15;
      if (mrow + 0 < MM) unsafeAtomicAdd(&outf[(size_t)o4.x * C_OUT + col], v[0]);
      if (mrow + 1 < MM) unsafeAtomicAdd(&outf[(size_t)o4.y * C_OUT + col], v[1]);
      if (mrow + 2 < MM) unsafeAtomicAdd(&outf[(size_t)o4.z * C_OUT + col], v[2]);
      if (mrow + 3 < MM) unsafeAtomicAdd(&outf[(size_t)o4.w * C_OUT + col], v[3]);
    }
  }
}

// ---------- fp32 reductions / finalize ----------
__global__ void stats_kernel(const float* __restrict__ out, float* __restrict__ ws) {
  __shared__ float ls[4][64];
  __shared__ float ls2[4][64];
  int t = threadIdx.x;
  int c = t & 63, sub = t >> 6;
  float s = 0.f, s2 = 0.f;
  for (int r = blockIdx.x * 4 + sub; r < N_OUT; r += gridDim.x * 4) {
    float v = out[(size_t)r * C_OUT + c];
    s += v; s2 += v * v;
  }
  ls[sub][c] = s; ls2[sub][c] = s2;
  __syncthreads();
  if (t < 64) {
    float ts = ls[0][t] + ls[1][t] + ls[2][t] + ls[3][t];
    float t2 = ls2[0][t] + ls2[1][t] + ls2[2][t] + ls2[3][t];
    unsafeAtomicAdd(&ws[t], ts);
    unsafeAtomicAdd(&ws[64 + t], t2);
  }
}

__global__ void finalize_kernel(float* __restrict__ out, const float* __restrict__ ws) {
  int i = blockIdx.x * 256 + threadIdx.x;
  float4 v = ((const float4*)out)[i];
  int c0 = (i & 15) * 4;
  float s0 = ws[128 + c0], s1 = ws[129 + c0], s2 = ws[130 + c0], s3 = ws[131 + c0];
  float b0 = ws[192 + c0], b1 = ws[193 + c0], b2 = ws[194 + c0], b3 = ws[195 + c0];
  v.x = fmaxf(fmaf(v.x, s0, b0), 0.f);
  v.y = fmaxf(fmaf(v.y, s1, b1), 0.f);
  v.z = fmaxf(fmaf(v.z, s2, b2), 0.f);
  v.w = fmaxf(fmaf(v.w, s3, b3), 0.f);
  ((float4*)out)[i] = v;
}

__global__ void prep_kernel(float* __restrict__ ws,
                            const float* __restrict__ gamma,
                            const float* __restrict__ beta) {
  int c = threadIdx.x;
  float mean = ws[c] * (1.0f / N_OUT);
  float var  = ws[64 + c] * (1.0f / N_OUT) - mean * mean;
  var = fmaxf(var, 0.0f);
  float sc = gamma[c] * rsqrtf(var + BN_EPS);
  ws[128 + c] = sc;
  ws[192 + c] = beta[c] - mean * sc;
}

extern "C" void kernel_launch(void* const* d_in, const int* in_sizes, int n_in,
                              void* d_out, int out_size, void* d_ws, size_t ws_size,
                              hipStream_t stream) {
  const float* x      = (const float*)d_in[0];
  const float* weight = (const float*)d_in[1];
  const float* gamma  = (const float*)d_in[2];
  const float* beta   = (const float*)d_in[3];
  const int* in_map   = (const int*)d_in[4];
  const int* out_map  = (const int*)d_in[5];
  float* out   = (float*)d_out;
  float* stats = (float*)d_ws;

  const size_t WT_OFF  = 4096;                       // 442 KB of bf16 weights
  const size_t CNT_OFF = 512u * 1024;                // 216 KB counters
  const size_t OFF_OFF = 768u * 1024;                // 216 KB padded offsets
  const size_t CUR_OFF = 1024u * 1024;               // 216 KB cursors
  const size_t XB_OFF  = 2u * 1024 * 1024;           // 25.6 MB bf16 x
  const size_t XB_SZ   = (size_t)N_IN * C_IN * 2;
  const size_t REC_OFF = 28u * 1024 * 1024;          // 14.4 MB records
  const size_t REC_SZ  = (size_t)RECCAP * 4;
  const size_t NEED    = REC_OFF + REC_SZ;

  unsigned* wt  = (unsigned*)((char*)d_ws + WT_OFF);
  int* cnt      = (int*)((char*)d_ws + CNT_OFF);
  int* off      = (int*)((char*)d_ws + OFF_OFF);
  int* cur      = (int*)((char*)d_ws + CUR_OFF);
  unsigned* xb  = (unsigned*)((char*)d_ws + XB_OFF);
  unsigned* rec = (unsigned*)((char*)d_ws + REC_OFF);

  hipMemsetAsync(d_ws, 0, 1024, stream);

  if (ws_size >= NEED) {
    // main path: CSR sort by (out_tile, k) + LDS-accumulated tile GEMM
    hipMemsetAsync(cnt, 0, (NBINS + 1) * sizeof(int), stream);
    hipMemsetAsync(rec, 0x80, REC_SZ, stream);       // pad slots => invalid
    convert_kernel<<<6682, 256, 0, stream>>>(x, xb, weight, wt, 6250);
    hist_kernel<<<dim3((MM + 255) / 256, NK), 256, 0, stream>>>(out_map, cnt);
    scan_kernel<<<1, 256, 0, stream>>>(cnt, off, cur);
    scatter_rec_kernel<<<dim3((MM + 255) / 256, NK), 256, 0, stream>>>(
        in_map, out_map, cur, rec);
    conv_tile_kernel<<<NTILE, 256, 0, stream>>>((const uint4*)xb,
        (const unsigned short*)wt, rec, off, out, stats);
    prep_kernel<<<1, 64, 0, stream>>>(stats, gamma, beta);
    finalize_kernel<<<(N_OUT * C_OUT / 4 + 255) / 256, 256, 0, stream>>>(out, stats);
  } else {
    // fallback: fp32 atomics into d_out (weight conversion only)
    hipMemsetAsync(d_out, 0, (size_t)N_OUT * C_OUT * sizeof(float), stream);
    convert_kernel<<<432, 256, 0, stream>>>(x, xb, weight, wt, 0);
    dim3 g((MM + TILE_M - 1) / TILE_M, NK);
    scatter_f32_kernel<<<g, 256, 0, stream>>>(x, (const unsigned short*)wt,
                                              in_map, out_map, out);
    stats_kernel<<<512, 256, 0, stream>>>(out, stats);
    prep_kernel<<<1, 64, 0, stream>>>(stats, gamma, beta);
    finalize_kernel<<<(N_OUT * C_OUT / 4 + 255) / 256, 256, 0, stream>>>(out, stats);
  }
}

// Round 2
// 1480.238 us; speedup vs baseline: 2.7985x; 2.7985x over previous
//
#include <hip/hip_runtime.h>
#include <hip/hip_fp16.h>

#define N_IN   100000
#define N_OUT  200000
#define C_IN   128
#define C_OUT  64
#define NK     27
#define MM     100000
#define BN_EPS 1e-5f

#define TILE_M 128   // fallback path tile
#define APAD   136   // fallback LDS row stride (bf16 elems)

// ---- sorted-CSR main path geometry ----
#define TILE_R 100           // output rows per tile (2000*100 == N_OUT exactly)
#define NTILE  2000
#define NBINS  (NTILE * NK)  // 54000 bins keyed by (tile, k)
#define LROW   68            // LDS accumulator row stride in floats (pad vs 64)
#define RECCAP 3600000       // >= 2.7M + NBINS*15 worst-case padded records
#define CHCAP  320           // per-tile chunk-table capacity (mean ~100, +9 sigma)

typedef short bf16x8 __attribute__((ext_vector_type(8)));
typedef float f32x4  __attribute__((ext_vector_type(4)));

__device__ __forceinline__ unsigned pack2_bf16(float a, float b) {
  unsigned ua = __float_as_uint(a);
  unsigned ub = __float_as_uint(b);
  ua = (ua + 0x7FFFu + ((ua >> 16) & 1u)) >> 16;          // low half
  ub = (ub + 0x7FFFu + ((ub >> 16) & 1u)) & 0xFFFF0000u;  // high half
  return ua | ub;
}

// Combined converter:
//  blocks [0, xblocks):  x f32 [N_IN][C_IN] -> xb bf16 (packed pairs), 8 floats/thread
//  blocks [xblocks, ...): weight [k][ci][co] f32 -> wt [k][co][ci] bf16
__global__ void convert_kernel(const float* __restrict__ x, unsigned* __restrict__ xb,
                               const float* __restrict__ w, unsigned* __restrict__ wt,
                               int xblocks) {
  if ((int)blockIdx.x < xblocks) {
    int id = blockIdx.x * 256 + threadIdx.x;          // [0, 1.6M)
    const float4* xs = (const float4*)x;
    float4 v0 = xs[2 * id];
    float4 v1 = xs[2 * id + 1];
    uint4 o;
    o.x = pack2_bf16(v0.x, v0.y);
    o.y = pack2_bf16(v0.z, v0.w);
    o.z = pack2_bf16(v1.x, v1.y);
    o.w = pack2_bf16(v1.z, v1.w);
    ((uint4*)xb)[id] = o;
  } else {
    int pidx = (blockIdx.x - xblocks) * 256 + threadIdx.x;  // [0, 27*4096)
    int k   = pidx >> 12;
    int rem = pidx & 4095;
    int co  = rem >> 6;
    int ci0 = (rem & 63) * 2;
    const float* wk = w + (size_t)k * C_IN * C_OUT;
    float a = wk[ci0 * C_OUT + co];
    float b = wk[(ci0 + 1) * C_OUT + co];
    wt[pidx] = pack2_bf16(a, b);
  }
}

// ---------- phase A: counting sort of (k,m) pairs by (out_tile, k) ----------
__global__ void hist_kernel(const int* __restrict__ out_map, int* __restrict__ cnt) {
  int m = blockIdx.x * 256 + threadIdx.x;
  int k = blockIdx.y;
  if (m < MM) {
    int o = out_map[k * MM + m];
    atomicAdd(&cnt[(o / TILE_R) * NK + k], 1);
  }
}

// single-block exclusive scan over NBINS bins; each bin padded to multiple of 16
__global__ void scan_kernel(const int* __restrict__ cnt,
                            int* __restrict__ off,
                            int* __restrict__ cur) {
  __shared__ int part[256];
  const int t = threadIdx.x;
  const int PER = (NBINS + 255) / 256;  // 211
  const int s0 = t * PER;
  const int s1 = (s0 + PER < NBINS) ? (s0 + PER) : NBINS;
  int sum = 0;
  for (int i = s0; i < s1; ++i) sum += (cnt[i] + 15) & ~15;
  part[t] = sum;
  __syncthreads();
  if (t == 0) {
    int acc = 0;
    for (int i = 0; i < 256; ++i) { int v = part[i]; part[i] = acc; acc += v; }
  }
  __syncthreads();
  int run = part[t];
  for (int i = s0; i < s1; ++i) {
    off[i] = run; cur[i] = run;
    run += (cnt[i] + 15) & ~15;
  }
  if (s1 == NBINS) off[NBINS] = run;
}

// rec = (in << 7) | out_local; bit31 set == invalid (pad slots stay 0x80808080)
__global__ void scatter_rec_kernel(const int* __restrict__ in_map,
                                   const int* __restrict__ out_map,
                                   int* __restrict__ cur,
                                   unsigned* __restrict__ rec) {
  int m = blockIdx.x * 256 + threadIdx.x;
  int k = blockIdx.y;
  if (m < MM) {
    int o = out_map[k * MM + m];
    int tile = o / TILE_R;
    int ol = o - tile * TILE_R;
    int pos = atomicAdd(&cur[tile * NK + k], 1);
    rec[pos] = ((unsigned)in_map[k * MM + m] << 7) | (unsigned)ol;
  }
}

// ---------- phase B: per-tile gather-GEMM with LDS accumulation ----------
// Wave-per-chunk decomposition: each wave owns disjoint 16-record chunks and
// computes the full 16x64 contribution with K=128 accumulated in MFMA C-regs
// (16 chained MFMAs; B in 64 VGPRs, reloaded only on k-change — chunks are
// k-sorted).  Scatter uses ds_add_f32 (no CAS, no systematic contention).
__global__ __launch_bounds__(256) void conv_tile_kernel(
    const uint4* __restrict__ xb,            // [N_IN][16] 16B-chunks (256 B/row)
    const unsigned short* __restrict__ wt,   // [k][co][ci] bf16
    const unsigned* __restrict__ rec,
    const int* __restrict__ off,
    float* __restrict__ out,
    float* __restrict__ ws)
{
  __shared__ float Lacc[TILE_R * LROW];      // 27.2 KB
  __shared__ float red[2][4][64];            // 2 KB, BN partial sums
  __shared__ int chtab[CHCAP];               // flattened chunk table
  __shared__ int nch_s;

  const int t    = threadIdx.x;
  const int tile = blockIdx.x;
  const int wave = t >> 6;
  const int lane = t & 63;
  const int quad = lane >> 4;
  const int l15  = lane & 15;

  for (int i = t; i < TILE_R * LROW; i += 256) Lacc[i] = 0.f;

  // wave 0: build chunk table (k-sorted since bins are k-ordered)
  if (wave == 0) {
    int cnt = 0, s0 = 0;
    if (lane < NK) {
      s0  = off[tile * NK + lane];
      cnt = (off[tile * NK + lane + 1] - s0) >> 4;
    }
    int pos = cnt;
    #pragma unroll
    for (int d = 1; d < 64; d <<= 1) {
      int n = __shfl_up(pos, d);
      if (lane >= d) pos += n;
    }
    int base = pos - cnt;
    for (int i = 0; i < cnt; ++i)
      chtab[base + i] = (lane << 24) | (s0 + (i << 4));
    if (lane == NK - 1) nch_s = pos;
  }
  __syncthreads();

  const int nch = nch_s;
  const int cs  = (nch * wave) >> 2;
  const int ce  = (nch * (wave + 1)) >> 2;
  const unsigned lbase = (unsigned)(unsigned long long)(void*)Lacc;

  int kcur = -1;
  bf16x8 B[4][4];
  unsigned ent0 = 0, ent1 = 0;
  unsigned r0 = 0x80808080u, r1 = 0x80808080u;
  uint4 a0[4], a1[4];

  if (cs < ce) {
    ent0 = (unsigned)chtab[cs];
    r0 = rec[(ent0 & 0xFFFFFFu) + l15];
    unsigned row0 = (r0 & 0x80000000u) ? 0u : (r0 >> 7);
    #pragma unroll
    for (int kk = 0; kk < 4; ++kk) a0[kk] = xb[(size_t)row0 * 16 + kk * 4 + quad];
    if (cs + 1 < ce) {
      ent1 = (unsigned)chtab[cs + 1];
      r1 = rec[(ent1 & 0xFFFFFFu) + l15];
    }
  }

  for (int ci = cs; ci < ce; ++ci) {
    // prefetch rec for ci+2, A for ci+1
    unsigned ent2 = 0, r2 = 0x80808080u;
    if (ci + 2 < ce) {
      ent2 = (unsigned)chtab[ci + 2];
      r2 = rec[(ent2 & 0xFFFFFFu) + l15];
    }
    if (ci + 1 < ce) {
      unsigned row1 = (r1 & 0x80000000u) ? 0u : (r1 >> 7);
      #pragma unroll
      for (int kk = 0; kk < 4; ++kk) a1[kk] = xb[(size_t)row1 * 16 + kk * 4 + quad];
    }
    const int k = (int)(ent0 >> 24);
    if (k != kcur) {                // wave-uniform branch
      kcur = k;
      const unsigned short* wk = wt + (size_t)k * (C_OUT * C_IN) + l15 * C_IN + quad * 8;
      #pragma unroll
      for (int ct = 0; ct < 4; ++ct)
        #pragma unroll
        for (int kk = 0; kk < 4; ++kk)
          B[ct][kk] = *(const bf16x8*)(wk + ct * 16 * C_IN + kk * 32);
    }
    f32x4 acc0 = (f32x4){0.f,0.f,0.f,0.f};
    f32x4 acc1 = (f32x4){0.f,0.f,0.f,0.f};
    f32x4 acc2 = (f32x4){0.f,0.f,0.f,0.f};
    f32x4 acc3 = (f32x4){0.f,0.f,0.f,0.f};
    #pragma unroll
    for (int kk = 0; kk < 4; ++kk) {
      bf16x8 fa = *(const bf16x8*)&a0[kk];
      acc0 = __builtin_amdgcn_mfma_f32_16x16x32_bf16(fa, B[0][kk], acc0, 0, 0, 0);
      acc1 = __builtin_amdgcn_mfma_f32_16x16x32_bf16(fa, B[1][kk], acc1, 0, 0, 0);
      acc2 = __builtin_amdgcn_mfma_f32_16x16x32_bf16(fa, B[2][kk], acc2, 0, 0, 0);
      acc3 = __builtin_amdgcn_mfma_f32_16x16x32_bf16(fa, B[3][kk], acc3, 0, 0, 0);
    }
    // D layout: col = l15 (+ct*16), row = quad*4 + reg.  rec for row j in lane j.
    #pragma unroll
    for (int i = 0; i < 4; ++i) {
      unsigned rr = __shfl(r0, quad * 4 + i);
      if (!(rr & 0x80000000u)) {
        unsigned dst = lbase + ((rr & 127u) * LROW + l15) * 4u;
        asm volatile("ds_add_f32 %0, %1"            :: "v"(dst), "v"(acc0[i]) : "memory");
        asm volatile("ds_add_f32 %0, %1 offset:64"  :: "v"(dst), "v"(acc1[i]) : "memory");
        asm volatile("ds_add_f32 %0, %1 offset:128" :: "v"(dst), "v"(acc2[i]) : "memory");
        asm volatile("ds_add_f32 %0, %1 offset:192" :: "v"(dst), "v"(acc3[i]) : "memory");
      }
    }
    ent0 = ent1; r0 = r1;
    #pragma unroll
    for (int kk = 0; kk < 4; ++kk) a0[kk] = a1[kk];
    ent1 = ent2; r1 = r2;
  }

  // drain asm ds_add ops (invisible to the compiler's waitcnt pass)
  asm volatile("s_waitcnt lgkmcnt(0)" ::: "memory");
  __syncthreads();

  // fused BN statistics: column sums / sumsq over this tile's 100 rows
  {
    const int col = t & 63, g = t >> 6;
    float s = 0.f, q = 0.f;
    for (int r = g; r < TILE_R; r += 4) {
      float v = Lacc[r * LROW + col];
      s += v; q += v * v;
    }
    red[0][g][col] = s; red[1][g][col] = q;
  }
  __syncthreads();
  if (t < 64) {
    float S = red[0][0][t] + red[0][1][t] + red[0][2][t] + red[0][3][t];
    float Q = red[1][0][t] + red[1][1][t] + red[1][2][t] + red[1][3][t];
    unsafeAtomicAdd(&ws[t], S);
    unsafeAtomicAdd(&ws[64 + t], Q);
  }
  // non-atomic tile store (rows exclusively owned)
  for (int idx = t; idx < TILE_R * 16; idx += 256) {
    int r = idx >> 4, c4 = idx & 15;
    float4 v = *(const float4*)&Lacc[r * LROW + c4 * 4];
    ((float4*)out)[(size_t)(tile * TILE_R + r) * 16 + c4] = v;
  }
}

// ---------- legacy fallback (fp32 atomics into d_out) ----------
__global__ __launch_bounds__(256) void scatter_f32_kernel(
    const float* __restrict__ x,
    const unsigned short* __restrict__ wt,
    const int* __restrict__ in_map,
    const int* __restrict__ out_map,
    float* __restrict__ outf)
{
  __shared__ unsigned short Als[TILE_M * APAD];
  __shared__ unsigned short Bls[C_OUT * APAD];
  __shared__ int om[TILE_M];

  const int t = threadIdx.x;
  const int k = blockIdx.y;
  const int mbase = blockIdx.x * TILE_M;

  if (t < TILE_M) {
    int m = mbase + t;
    om[t] = (m < MM) ? out_map[k * MM + m] : 0;
  }
  {
    const uint4* src = (const uint4*)(wt + (size_t)k * C_OUT * C_IN);
    #pragma unroll
    for (int i = 0; i < 4; ++i) {
      int ch  = t + i * 256;
      int co  = ch >> 4;
      int ci0 = (ch & 15) * 8;
      *(uint4*)&Bls[co * APAD + ci0] = src[ch];
    }
  }
  {
    int r    = t >> 1;
    int half = t & 1;
    int m    = mbase + r;
    int src  = (m < MM) ? in_map[k * MM + m] : 0;
    const float4* xr = (const float4*)(x + (size_t)src * C_IN) + half * 16;
    uint2* dst = (uint2*)&Als[r * APAD + half * 64];
    #pragma unroll
    for (int j = 0; j < 16; ++j) {
      float4 v = xr[j];
      dst[j] = make_uint2(pack2_bf16(v.x, v.y), pack2_bf16(v.z, v.w));
    }
  }
  __syncthreads();

  const int wave = t >> 6;
  const int lane = t & 63;
  const int quad = lane >> 4;
  const int l15  = lane & 15;
  const int rb   = wave * 32;

  f32x4 acc[2][4];
  #pragma unroll
  for (int i = 0; i < 2; ++i)
    #pragma unroll
    for (int j = 0; j < 4; ++j)
      acc[i][j] = (f32x4){0.f, 0.f, 0.f, 0.f};

  #pragma unroll
  for (int kk = 0; kk < 4; ++kk) {
    const int koff = kk * 32 + quad * 8;
    bf16x8 a0 = *(const bf16x8*)&Als[(rb + l15) * APAD + koff];
    bf16x8 a1 = *(const bf16x8*)&Als[(rb + 16 + l15) * APAD + koff];
    bf16x8 b0 = *(const bf16x8*)&Bls[(l15) * APAD + koff];
    bf16x8 b1 = *(const bf16x8*)&Bls[(16 + l15) * APAD + koff];
    bf16x8 b2 = *(const bf16x8*)&Bls[(32 + l15) * APAD + koff];
    bf16x8 b3 = *(const bf16x8*)&Bls[(48 + l15) * APAD + koff];
    acc[0][0] = __builtin_amdgcn_mfma_f32_16x16x32_bf16(a0, b0, acc[0][0], 0, 0, 0);
    acc[0][1] = __builtin_amdgcn_mfma_f32_16x16x32_bf16(a0, b1, acc[0][1], 0, 0, 0);
    acc[0][2] = __builtin_amdgcn_mfma_f32_16x16x32_bf16(a0, b2, acc[0][2], 0, 0, 0);
    acc[0][3] = __builtin_amdgcn_mfma_f32_16x16x32_bf16(a0, b3, acc[0][3], 0, 0, 0);
    acc[1][0] = __builtin_amdgcn_mfma_f32_16x16x32_bf16(a1, b0, acc[1][0], 0, 0, 0);
    acc[1][1] = __builtin_amdgcn_mfma_f32_16x16x32_bf16(a1, b1, acc[1][1], 0, 0, 0);
    acc[1][2] = __builtin_amdgcn_mfma_f32_16x16x32_bf16(a1, b2, acc[1][2], 0, 0, 0);
    acc[1][3] = __builtin_amdgcn_mfma_f32_16x16x32_bf16(a1, b3, acc[1][3], 0, 0, 0);
  }

  #pragma unroll
  for (int rt = 0; rt < 2; ++rt) {
    int rloc = rb + rt * 16 + quad * 4;
    int4 o4 = *(const int4*)&om[rloc];
    int mrow = mbase + rloc;
    #pragma unroll
    for (int ct = 0; ct < 4; ++ct) {
      f32x4 v = acc[rt][ct];
      int col = ct * 16 + l15;
      if (mrow + 0 < MM) unsafeAtomicAdd(&outf[(size_t)o4.x * C_OUT + col], v[0]);
      if (mrow + 1 < MM) unsafeAtomicAdd(&outf[(size_t)o4.y * C_OUT + col], v[1]);
      if (mrow + 2 < MM) unsafeAtomicAdd(&outf[(size_t)o4.z * C_OUT + col], v[2]);
      if (mrow + 3 < MM) unsafeAtomicAdd(&outf[(size_t)o4.w * C_OUT + col], v[3]);
    }
  }
}

// ---------- fp32 reductions / finalize ----------
__global__ void stats_kernel(const float* __restrict__ out, float* __restrict__ ws) {
  __shared__ float ls[4][64];
  __shared__ float ls2[4][64];
  int t = threadIdx.x;
  int c = t & 63, sub = t >> 6;
  float s = 0.f, s2 = 0.f;
  for (int r = blockIdx.x * 4 + sub; r < N_OUT; r += gridDim.x * 4) {
    float v = out[(size_t)r * C_OUT + c];
    s += v; s2 += v * v;
  }
  ls[sub][c] = s; ls2[sub][c] = s2;
  __syncthreads();
  if (t < 64) {
    float ts = ls[0][t] + ls[1][t] + ls[2][t] + ls[3][t];
    float t2 = ls2[0][t] + ls2[1][t] + ls2[2][t] + ls2[3][t];
    unsafeAtomicAdd(&ws[t], ts);
    unsafeAtomicAdd(&ws[64 + t], t2);
  }
}

__global__ void finalize_kernel(float* __restrict__ out, const float* __restrict__ ws) {
  int i = blockIdx.x * 256 + threadIdx.x;
  float4 v = ((const float4*)out)[i];
  int c0 = (i & 15) * 4;
  float s0 = ws[128 + c0], s1 = ws[129 + c0], s2 = ws[130 + c0], s3 = ws[131 + c0];
  float b0 = ws[192 + c0], b1 = ws[193 + c0], b2 = ws[194 + c0], b3 = ws[195 + c0];
  v.x = fmaxf(fmaf(v.x, s0, b0), 0.f);
  v.y = fmaxf(fmaf(v.y, s1, b1), 0.f);
  v.z = fmaxf(fmaf(v.z, s2, b2), 0.f);
  v.w = fmaxf(fmaf(v.w, s3, b3), 0.f);
  ((float4*)out)[i] = v;
}

__global__ void prep_kernel(float* __restrict__ ws,
                            const float* __restrict__ gamma,
                            const float* __restrict__ beta) {
  int c = threadIdx.x;
  float mean = ws[c] * (1.0f / N_OUT);
  float var  = ws[64 + c] * (1.0f / N_OUT) - mean * mean;
  var = fmaxf(var, 0.0f);
  float sc = gamma[c] * rsqrtf(var + BN_EPS);
  ws[128 + c] = sc;
  ws[192 + c] = beta[c] - mean * sc;
}

extern "C" void kernel_launch(void* const* d_in, const int* in_sizes, int n_in,
                              void* d_out, int out_size, void* d_ws, size_t ws_size,
                              hipStream_t stream) {
  const float* x      = (const float*)d_in[0];
  const float* weight = (const float*)d_in[1];
  const float* gamma  = (const float*)d_in[2];
  const float* beta   = (const float*)d_in[3];
  const int* in_map   = (const int*)d_in[4];
  const int* out_map  = (const int*)d_in[5];
  float* out   = (float*)d_out;
  float* stats = (float*)d_ws;

  const size_t WT_OFF  = 4096;                       // 442 KB of bf16 weights
  const size_t CNT_OFF = 512u * 1024;                // 216 KB counters
  const size_t OFF_OFF = 768u * 1024;                // 216 KB padded offsets
  const size_t CUR_OFF = 1024u * 1024;               // 216 KB cursors
  const size_t XB_OFF  = 2u * 1024 * 1024;           // 25.6 MB bf16 x
  const size_t XB_SZ   = (size_t)N_IN * C_IN * 2;
  const size_t REC_OFF = 28u * 1024 * 1024;          // 14.4 MB records
  const size_t REC_SZ  = (size_t)RECCAP * 4;
  const size_t NEED    = REC_OFF + REC_SZ;

  unsigned* wt  = (unsigned*)((char*)d_ws + WT_OFF);
  int* cnt      = (int*)((char*)d_ws + CNT_OFF);
  int* off      = (int*)((char*)d_ws + OFF_OFF);
  int* cur      = (int*)((char*)d_ws + CUR_OFF);
  unsigned* xb  = (unsigned*)((char*)d_ws + XB_OFF);
  unsigned* rec = (unsigned*)((char*)d_ws + REC_OFF);

  hipMemsetAsync(d_ws, 0, 1024, stream);

  if (ws_size >= NEED) {
    // main path: CSR sort by (out_tile, k) + LDS-accumulated tile GEMM
    hipMemsetAsync(cnt, 0, (NBINS + 1) * sizeof(int), stream);
    hipMemsetAsync(rec, 0x80, REC_SZ, stream);       // pad slots => invalid
    convert_kernel<<<6682, 256, 0, stream>>>(x, xb, weight, wt, 6250);
    hist_kernel<<<dim3((MM + 255) / 256, NK), 256, 0, stream>>>(out_map, cnt);
    scan_kernel<<<1, 256, 0, stream>>>(cnt, off, cur);
    scatter_rec_kernel<<<dim3((MM + 255) / 256, NK), 256, 0, stream>>>(
        in_map, out_map, cur, rec);
    conv_tile_kernel<<<NTILE, 256, 0, stream>>>((const uint4*)xb,
        (const unsigned short*)wt, rec, off, out, stats);
    prep_kernel<<<1, 64, 0, stream>>>(stats, gamma, beta);
    finalize_kernel<<<(N_OUT * C_OUT / 4 + 255) / 256, 256, 0, stream>>>(out, stats);
  } else {
    // fallback: fp32 atomics into d_out (weight conversion only)
    hipMemsetAsync(d_out, 0, (size_t)N_OUT * C_OUT * sizeof(float), stream);
    convert_kernel<<<432, 256, 0, stream>>>(x, xb, weight, wt, 0);
    dim3 g((MM + TILE_M - 1) / TILE_M, NK);
    scatter_f32_kernel<<<g, 256, 0, stream>>>(x, (const unsigned short*)wt,
                                              in_map, out_map, out);
    stats_kernel<<<512, 256, 0, stream>>>(out, stats);
    prep_kernel<<<1, 64, 0, stream>>>(stats, gamma, beta);
    finalize_kernel<<<(N_OUT * C_OUT / 4 + 255) / 256, 256, 0, stream>>>(out, stats);
  }
}

// Round 3
// 1319.768 us; speedup vs baseline: 3.1388x; 1.1216x over previous
//
#include <hip/hip_runtime.h>
#include <hip/hip_fp16.h>

#define N_IN   100000
#define N_OUT  200000
#define C_IN   128
#define C_OUT  64
#define NK     27
#define MM     100000
#define BN_EPS 1e-5f

#define TILE_M 128   // fallback path tile
#define APAD   136   // fallback LDS row stride (bf16 elems)

// ---- sorted-CSR main path geometry ----
#define TILE_R 100           // output rows per tile (2000*100 == N_OUT exactly)
#define NTILE  2000
#define CAP_T  2048          // fixed per-tile record capacity (mean ~1755 padded, 8-sigma safe)
#define LROW   68            // LDS accumulator row stride in floats (pad vs 64)
#define CHCAP  160           // per-tile chunk-table capacity (max CAP_T/16 = 128)

typedef short bf16x8 __attribute__((ext_vector_type(8)));
typedef float f32x4  __attribute__((ext_vector_type(4)));

__device__ __forceinline__ unsigned pack2_bf16(float a, float b) {
  unsigned ua = __float_as_uint(a);
  unsigned ub = __float_as_uint(b);
  ua = (ua + 0x7FFFu + ((ua >> 16) & 1u)) >> 16;          // low half
  ub = (ub + 0x7FFFu + ((ub >> 16) & 1u)) & 0xFFFF0000u;  // high half
  return ua | ub;
}

// Combined converter:
//  blocks [0, xblocks):  x f32 [N_IN][C_IN] -> xb bf16 (packed pairs), 8 floats/thread
//  blocks [xblocks, ...): weight [k][ci][co] f32 -> wt [k][co][ci] bf16
__global__ void convert_kernel(const float* __restrict__ x, unsigned* __restrict__ xb,
                               const float* __restrict__ w, unsigned* __restrict__ wt,
                               int xblocks) {
  if ((int)blockIdx.x < xblocks) {
    int id = blockIdx.x * 256 + threadIdx.x;          // [0, 1.6M)
    const float4* xs = (const float4*)x;
    float4 v0 = xs[2 * id];
    float4 v1 = xs[2 * id + 1];
    uint4 o;
    o.x = pack2_bf16(v0.x, v0.y);
    o.y = pack2_bf16(v0.z, v0.w);
    o.z = pack2_bf16(v1.x, v1.y);
    o.w = pack2_bf16(v1.z, v1.w);
    ((uint4*)xb)[id] = o;
  } else {
    int pidx = (blockIdx.x - xblocks) * 256 + threadIdx.x;  // [0, 27*4096)
    int k   = pidx >> 12;
    int rem = pidx & 4095;
    int co  = rem >> 6;
    int ci0 = (rem & 63) * 2;
    const float* wk = w + (size_t)k * C_IN * C_OUT;
    float a = wk[ci0 * C_OUT + co];
    float b = wk[(ci0 + 1) * C_OUT + co];
    wt[pidx] = pack2_bf16(a, b);
  }
}

// ---------- phase A: counting sort of (k,m) pairs by (out_tile, k) ----------
__global__ void hist_kernel(const int* __restrict__ out_map, int* __restrict__ cnt) {
  int m = blockIdx.x * 256 + threadIdx.x;
  int k = blockIdx.y;
  if (m < MM) {
    int o = out_map[k * MM + m];
    atomicAdd(&cnt[(o / TILE_R) * NK + k], 1);
  }
}

// per-tile 27-bin prefix via wave shuffle; each tile owns rec[tile*CAP_T ..)
// off layout: [tile][28] (28th entry = end of last bin)
__global__ void tile_scan_kernel(const int* __restrict__ cnt,
                                 int* __restrict__ off,
                                 int* __restrict__ cur) {
  int tile = blockIdx.x * 4 + (threadIdx.x >> 6);
  int lane = threadIdx.x & 63;
  if (tile >= NTILE) return;
  int c = 0;
  if (lane < NK) c = (cnt[tile * NK + lane] + 15) & ~15;   // pad to 16
  int p = c;                                               // inclusive scan
  #pragma unroll
  for (int d = 1; d < 32; d <<= 1) {
    int n = __shfl_up(p, d);
    if (lane >= d) p += n;
  }
  int base = tile * CAP_T + p - c;                         // exclusive
  if (lane < NK) { off[tile * 28 + lane] = base; cur[tile * 28 + lane] = base; }
  if (lane == NK - 1) off[tile * 28 + NK] = base + c;
}

// rec = (in << 7) | out_local; bit31 set == invalid (pad slots stay 0x80808080)
__global__ void scatter_rec_kernel(const int* __restrict__ in_map,
                                   const int* __restrict__ out_map,
                                   int* __restrict__ cur,
                                   unsigned* __restrict__ rec) {
  int m = blockIdx.x * 256 + threadIdx.x;
  int k = blockIdx.y;
  if (m < MM) {
    int o = out_map[k * MM + m];
    int tile = o / TILE_R;
    int ol = o - tile * TILE_R;
    int pos = atomicAdd(&cur[tile * 28 + k], 1);
    rec[pos] = ((unsigned)in_map[k * MM + m] << 7) | (unsigned)ol;
  }
}

// ---------- phase B: per-tile gather-GEMM with LDS accumulation ----------
// Wave-per-chunk decomposition; K=128 accumulated in MFMA C-regs (16 chained
// MFMAs; B in VGPRs, reloaded only on k-change).  LDS scatter via
// __hip_atomic_fetch_add (relaxed, workgroup) -> native ds_add, fully
// compiler-visible so the A/rec prefetch pipeline survives scheduling.
__global__ __launch_bounds__(256) void conv_tile_kernel(
    const uint4* __restrict__ xb,            // [N_IN][16] 16B-chunks (256 B/row)
    const unsigned short* __restrict__ wt,   // [k][co][ci] bf16
    const unsigned* __restrict__ rec,
    const int* __restrict__ off,
    float* __restrict__ out,
    float* __restrict__ ws)
{
  __shared__ float Lacc[TILE_R * LROW];      // 27.2 KB
  __shared__ float red[2][4][64];            // 2 KB, BN partial sums
  __shared__ int chtab[CHCAP];               // flattened chunk table
  __shared__ int nch_s;

  const int t    = threadIdx.x;
  const int tile = blockIdx.x;
  const int wave = t >> 6;
  const int lane = t & 63;
  const int quad = lane >> 4;
  const int l15  = lane & 15;

  for (int i = t; i < TILE_R * LROW; i += 256) Lacc[i] = 0.f;

  // wave 0: build chunk table (k-sorted since bins are k-ordered)
  if (wave == 0) {
    int cnt = 0, s0 = 0;
    if (lane < NK) {
      s0  = off[tile * 28 + lane];
      cnt = (off[tile * 28 + lane + 1] - s0) >> 4;
    }
    int pos = cnt;
    #pragma unroll
    for (int d = 1; d < 32; d <<= 1) {
      int n = __shfl_up(pos, d);
      if (lane >= d) pos += n;
    }
    int base = pos - cnt;
    for (int i = 0; i < cnt; ++i)
      chtab[base + i] = (lane << 24) | ((s0 + (i << 4)) & 0xFFFFFF);
    if (lane == NK - 1) nch_s = pos;
  }
  __syncthreads();

  const int nch = nch_s;
  const int cs  = (nch * wave) >> 2;
  const int ce  = (nch * (wave + 1)) >> 2;
  const unsigned recbase = (unsigned)tile * CAP_T & 0xFF000000u;  // high bits of tile region

  int kcur = -1;
  bf16x8 B[4][4];
  unsigned ent0 = 0, ent1 = 0;
  unsigned r0 = 0x80808080u, r1 = 0x80808080u;
  uint4 a0[4], a1[4];

  if (cs < ce) {
    ent0 = (unsigned)chtab[cs];
    r0 = rec[(ent0 & 0xFFFFFFu) + l15];
    unsigned row0 = (r0 & 0x80000000u) ? 0u : (r0 >> 7);
    #pragma unroll
    for (int kk = 0; kk < 4; ++kk) a0[kk] = xb[(size_t)row0 * 16 + kk * 4 + quad];
    if (cs + 1 < ce) {
      ent1 = (unsigned)chtab[cs + 1];
      r1 = rec[(ent1 & 0xFFFFFFu) + l15];
    }
  }

  for (int ci = cs; ci < ce; ++ci) {
    // prefetch rec for ci+2, A for ci+1
    unsigned ent2 = 0, r2 = 0x80808080u;
    if (ci + 2 < ce) {
      ent2 = (unsigned)chtab[ci + 2];
      r2 = rec[(ent2 & 0xFFFFFFu) + l15];
    }
    if (ci + 1 < ce) {
      unsigned row1 = (r1 & 0x80000000u) ? 0u : (r1 >> 7);
      #pragma unroll
      for (int kk = 0; kk < 4; ++kk) a1[kk] = xb[(size_t)row1 * 16 + kk * 4 + quad];
    }
    const int k = (int)(ent0 >> 24);
    if (k != kcur) {                // wave-uniform branch
      kcur = k;
      const unsigned short* wk = wt + (size_t)k * (C_OUT * C_IN) + l15 * C_IN + quad * 8;
      #pragma unroll
      for (int ct = 0; ct < 4; ++ct)
        #pragma unroll
        for (int kk = 0; kk < 4; ++kk)
          B[ct][kk] = *(const bf16x8*)(wk + ct * 16 * C_IN + kk * 32);
    }
    f32x4 acc0 = (f32x4){0.f,0.f,0.f,0.f};
    f32x4 acc1 = (f32x4){0.f,0.f,0.f,0.f};
    f32x4 acc2 = (f32x4){0.f,0.f,0.f,0.f};
    f32x4 acc3 = (f32x4){0.f,0.f,0.f,0.f};
    #pragma unroll
    for (int kk = 0; kk < 4; ++kk) {
      bf16x8 fa = *(const bf16x8*)&a0[kk];
      acc0 = __builtin_amdgcn_mfma_f32_16x16x32_bf16(fa, B[0][kk], acc0, 0, 0, 0);
      acc1 = __builtin_amdgcn_mfma_f32_16x16x32_bf16(fa, B[1][kk], acc1, 0, 0, 0);
      acc2 = __builtin_amdgcn_mfma_f32_16x16x32_bf16(fa, B[2][kk], acc2, 0, 0, 0);
      acc3 = __builtin_amdgcn_mfma_f32_16x16x32_bf16(fa, B[3][kk], acc3, 0, 0, 0);
    }
    // D layout: col = l15 (+ct*16), row = quad*4 + reg.  rec for row j in lane j.
    #pragma unroll
    for (int i = 0; i < 4; ++i) {
      unsigned rr = __shfl(r0, quad * 4 + i);
      if (!(rr & 0x80000000u)) {
        float* dst = &Lacc[(rr & 127u) * LROW + l15];
        __hip_atomic_fetch_add(dst +  0, acc0[i], __ATOMIC_RELAXED, __HIP_MEMORY_SCOPE_WORKGROUP);
        __hip_atomic_fetch_add(dst + 16, acc1[i], __ATOMIC_RELAXED, __HIP_MEMORY_SCOPE_WORKGROUP);
        __hip_atomic_fetch_add(dst + 32, acc2[i], __ATOMIC_RELAXED, __HIP_MEMORY_SCOPE_WORKGROUP);
        __hip_atomic_fetch_add(dst + 48, acc3[i], __ATOMIC_RELAXED, __HIP_MEMORY_SCOPE_WORKGROUP);
      }
    }
    ent0 = ent1; r0 = r1;
    #pragma unroll
    for (int kk = 0; kk < 4; ++kk) a0[kk] = a1[kk];
    ent1 = ent2; r1 = r2;
  }
  (void)recbase;
  __syncthreads();

  // fused BN statistics: column sums / sumsq over this tile's 100 rows
  {
    const int col = t & 63, g = t >> 6;
    float s = 0.f, q = 0.f;
    for (int r = g; r < TILE_R; r += 4) {
      float v = Lacc[r * LROW + col];
      s += v; q += v * v;
    }
    red[0][g][col] = s; red[1][g][col] = q;
  }
  __syncthreads();
  if (t < 64) {
    float S = red[0][0][t] + red[0][1][t] + red[0][2][t] + red[0][3][t];
    float Q = red[1][0][t] + red[1][1][t] + red[1][2][t] + red[1][3][t];
    unsafeAtomicAdd(&ws[t], S);
    unsafeAtomicAdd(&ws[64 + t], Q);
  }
  // non-atomic tile store (rows exclusively owned)
  for (int idx = t; idx < TILE_R * 16; idx += 256) {
    int r = idx >> 4, c4 = idx & 15;
    float4 v = *(const float4*)&Lacc[r * LROW + c4 * 4];
    ((float4*)out)[(size_t)(tile * TILE_R + r) * 16 + c4] = v;
  }
}

// ---------- legacy fallback (fp32 atomics into d_out) ----------
__global__ __launch_bounds__(256) void scatter_f32_kernel(
    const float* __restrict__ x,
    const unsigned short* __restrict__ wt,
    const int* __restrict__ in_map,
    const int* __restrict__ out_map,
    float* __restrict__ outf)
{
  __shared__ unsigned short Als[TILE_M * APAD];
  __shared__ unsigned short Bls[C_OUT * APAD];
  __shared__ int om[TILE_M];

  const int t = threadIdx.x;
  const int k = blockIdx.y;
  const int mbase = blockIdx.x * TILE_M;

  if (t < TILE_M) {
    int m = mbase + t;
    om[t] = (m < MM) ? out_map[k * MM + m] : 0;
  }
  {
    const uint4* src = (const uint4*)(wt + (size_t)k * C_OUT * C_IN);
    #pragma unroll
    for (int i = 0; i < 4; ++i) {
      int ch  = t + i * 256;
      int co  = ch >> 4;
      int ci0 = (ch & 15) * 8;
      *(uint4*)&Bls[co * APAD + ci0] = src[ch];
    }
  }
  {
    int r    = t >> 1;
    int half = t & 1;
    int m    = mbase + r;
    int src  = (m < MM) ? in_map[k * MM + m] : 0;
    const float4* xr = (const float4*)(x + (size_t)src * C_IN) + half * 16;
    uint2* dst = (uint2*)&Als[r * APAD + half * 64];
    #pragma unroll
    for (int j = 0; j < 16; ++j) {
      float4 v = xr[j];
      dst[j] = make_uint2(pack2_bf16(v.x, v.y), pack2_bf16(v.z, v.w));
    }
  }
  __syncthreads();

  const int wave = t >> 6;
  const int lane = t & 63;
  const int quad = lane >> 4;
  const int l15  = lane & 15;
  const int rb   = wave * 32;

  f32x4 acc[2][4];
  #pragma unroll
  for (int i = 0; i < 2; ++i)
    #pragma unroll
    for (int j = 0; j < 4; ++j)
      acc[i][j] = (f32x4){0.f, 0.f, 0.f, 0.f};

  #pragma unroll
  for (int kk = 0; kk < 4; ++kk) {
    const int koff = kk * 32 + quad * 8;
    bf16x8 a0 = *(const bf16x8*)&Als[(rb + l15) * APAD + koff];
    bf16x8 a1 = *(const bf16x8*)&Als[(rb + 16 + l15) * APAD + koff];
    bf16x8 b0 = *(const bf16x8*)&Bls[(l15) * APAD + koff];
    bf16x8 b1 = *(const bf16x8*)&Bls[(16 + l15) * APAD + koff];
    bf16x8 b2 = *(const bf16x8*)&Bls[(32 + l15) * APAD + koff];
    bf16x8 b3 = *(const bf16x8*)&Bls[(48 + l15) * APAD + koff];
    acc[0][0] = __builtin_amdgcn_mfma_f32_16x16x32_bf16(a0, b0, acc[0][0], 0, 0, 0);
    acc[0][1] = __builtin_amdgcn_mfma_f32_16x16x32_bf16(a0, b1, acc[0][1], 0, 0, 0);
    acc[0][2] = __builtin_amdgcn_mfma_f32_16x16x32_bf16(a0, b2, acc[0][2], 0, 0, 0);
    acc[0][3] = __builtin_amdgcn_mfma_f32_16x16x32_bf16(a0, b3, acc[0][3], 0, 0, 0);
    acc[1][0] = __builtin_amdgcn_mfma_f32_16x16x32_bf16(a1, b0, acc[1][0], 0, 0, 0);
    acc[1][1] = __builtin_amdgcn_mfma_f32_16x16x32_bf16(a1, b1, acc[1][1], 0, 0, 0);
    acc[1][2] = __builtin_amdgcn_mfma_f32_16x16x32_bf16(a1, b2, acc[1][2], 0, 0, 0);
    acc[1][3] = __builtin_amdgcn_mfma_f32_16x16x32_bf16(a1, b3, acc[1][3], 0, 0, 0);
  }

  #pragma unroll
  for (int rt = 0; rt < 2; ++rt) {
    int rloc = rb + rt * 16 + quad * 4;
    int4 o4 = *(const int4*)&om[rloc];
    int mrow = mbase + rloc;
    #pragma unroll
    for (int ct = 0; ct < 4; ++ct) {
      f32x4 v = acc[rt][ct];
      int col = ct * 16 + l15;
      if (mrow + 0 < MM) unsafeAtomicAdd(&outf[(size_t)o4.x * C_OUT + col], v[0]);
      if (mrow + 1 < MM) unsafeAtomicAdd(&outf[(size_t)o4.y * C_OUT + col], v[1]);
      if (mrow + 2 < MM) unsafeAtomicAdd(&outf[(size_t)o4.z * C_OUT + col], v[2]);
      if (mrow + 3 < MM) unsafeAtomicAdd(&outf[(size_t)o4.w * C_OUT + col], v[3]);
    }
  }
}

// ---------- fp32 reductions / finalize ----------
__global__ void stats_kernel(const float* __restrict__ out, float* __restrict__ ws) {
  __shared__ float ls[4][64];
  __shared__ float ls2[4][64];
  int t = threadIdx.x;
  int c = t & 63, sub = t >> 6;
  float s = 0.f, s2 = 0.f;
  for (int r = blockIdx.x * 4 + sub; r < N_OUT; r += gridDim.x * 4) {
    float v = out[(size_t)r * C_OUT + c];
    s += v; s2 += v * v;
  }
  ls[sub][c] = s; ls2[sub][c] = s2;
  __syncthreads();
  if (t < 64) {
    float ts = ls[0][t] + ls[1][t] + ls[2][t] + ls[3][t];
    float t2 = ls2[0][t] + ls2[1][t] + ls2[2][t] + ls2[3][t];
    unsafeAtomicAdd(&ws[t], ts);
    unsafeAtomicAdd(&ws[64 + t], t2);
  }
}

__global__ void finalize_kernel(float* __restrict__ out, const float* __restrict__ ws) {
  int i = blockIdx.x * 256 + threadIdx.x;
  float4 v = ((const float4*)out)[i];
  int c0 = (i & 15) * 4;
  float s0 = ws[128 + c0], s1 = ws[129 + c0], s2 = ws[130 + c0], s3 = ws[131 + c0];
  float b0 = ws[192 + c0], b1 = ws[193 + c0], b2 = ws[194 + c0], b3 = ws[195 + c0];
  v.x = fmaxf(fmaf(v.x, s0, b0), 0.f);
  v.y = fmaxf(fmaf(v.y, s1, b1), 0.f);
  v.z = fmaxf(fmaf(v.z, s2, b2), 0.f);
  v.w = fmaxf(fmaf(v.w, s3, b3), 0.f);
  ((float4*)out)[i] = v;
}

__global__ void prep_kernel(float* __restrict__ ws,
                            const float* __restrict__ gamma,
                            const float* __restrict__ beta) {
  int c = threadIdx.x;
  float mean = ws[c] * (1.0f / N_OUT);
  float var  = ws[64 + c] * (1.0f / N_OUT) - mean * mean;
  var = fmaxf(var, 0.0f);
  float sc = gamma[c] * rsqrtf(var + BN_EPS);
  ws[128 + c] = sc;
  ws[192 + c] = beta[c] - mean * sc;
}

extern "C" void kernel_launch(void* const* d_in, const int* in_sizes, int n_in,
                              void* d_out, int out_size, void* d_ws, size_t ws_size,
                              hipStream_t stream) {
  const float* x      = (const float*)d_in[0];
  const float* weight = (const float*)d_in[1];
  const float* gamma  = (const float*)d_in[2];
  const float* beta   = (const float*)d_in[3];
  const int* in_map   = (const int*)d_in[4];
  const int* out_map  = (const int*)d_in[5];
  float* out   = (float*)d_out;
  float* stats = (float*)d_ws;

  const size_t WT_OFF  = 4096;                       // 442 KB of bf16 weights
  const size_t CNT_OFF = 512u * 1024;                // 216 KB counters [tile][27]
  const size_t OFF_OFF = 768u * 1024;                // 224 KB offsets  [tile][28]
  const size_t CUR_OFF = 1024u * 1024;               // 224 KB cursors  [tile][28]
  const size_t XB_OFF  = 2u * 1024 * 1024;           // 25.6 MB bf16 x
  const size_t XB_SZ   = (size_t)N_IN * C_IN * 2;
  const size_t REC_OFF = 28u * 1024 * 1024;          // 16.4 MB records
  const size_t REC_SZ  = (size_t)NTILE * CAP_T * 4;
  const size_t NEED    = REC_OFF + REC_SZ;

  unsigned* wt  = (unsigned*)((char*)d_ws + WT_OFF);
  int* cnt      = (int*)((char*)d_ws + CNT_OFF);
  int* off      = (int*)((char*)d_ws + OFF_OFF);
  int* cur      = (int*)((char*)d_ws + CUR_OFF);
  unsigned* xb  = (unsigned*)((char*)d_ws + XB_OFF);
  unsigned* rec = (unsigned*)((char*)d_ws + REC_OFF);

  hipMemsetAsync(d_ws, 0, 1024, stream);

  if (ws_size >= NEED) {
    // main path: fixed-capacity per-tile CSR + LDS-accumulated tile GEMM
    hipMemsetAsync(cnt, 0, (size_t)NTILE * NK * sizeof(int), stream);
    hipMemsetAsync(rec, 0x80, REC_SZ, stream);       // pad slots => invalid
    convert_kernel<<<6682, 256, 0, stream>>>(x, xb, weight, wt, 6250);
    hist_kernel<<<dim3((MM + 255) / 256, NK), 256, 0, stream>>>(out_map, cnt);
    tile_scan_kernel<<<(NTILE + 3) / 4, 256, 0, stream>>>(cnt, off, cur);
    scatter_rec_kernel<<<dim3((MM + 255) / 256, NK), 256, 0, stream>>>(
        in_map, out_map, cur, rec);
    conv_tile_kernel<<<NTILE, 256, 0, stream>>>((const uint4*)xb,
        (const unsigned short*)wt, rec, off, out, stats);
    prep_kernel<<<1, 64, 0, stream>>>(stats, gamma, beta);
    finalize_kernel<<<(N_OUT * C_OUT / 4 + 255) / 256, 256, 0, stream>>>(out, stats);
  } else {
    // fallback: fp32 atomics into d_out (weight conversion only)
    hipMemsetAsync(d_out, 0, (size_t)N_OUT * C_OUT * sizeof(float), stream);
    convert_kernel<<<432, 256, 0, stream>>>(x, xb, weight, wt, 0);
    dim3 g((MM + TILE_M - 1) / TILE_M, NK);
    scatter_f32_kernel<<<g, 256, 0, stream>>>(x, (const unsigned short*)wt,
                                              in_map, out_map, out);
    stats_kernel<<<512, 256, 0, stream>>>(out, stats);
    prep_kernel<<<1, 64, 0, stream>>>(stats, gamma, beta);
    finalize_kernel<<<(N_OUT * C_OUT / 4 + 255) / 256, 256, 0, stream>>>(out, stats);
  }
}